// Round 11
// baseline (287.072 us; speedup 1.0000x reference)
//
#include <hip/hip_runtime.h>
#include <math.h>

#define NGRAPH 32
#define BLK 256

// ---- block-wide exclusive scan over 256 threads, 2 barriers (shfl-based) ----
__device__ __forceinline__ int block_scan_excl(int v, int tid, int* wsum, int& total) {
    int x = v;
#pragma unroll
    for (int d = 1; d < 64; d <<= 1) {
        int t = __shfl_up(x, d);
        if ((tid & 63) >= d) x += t;
    }
    if ((tid & 63) == 63) wsum[tid >> 6] = x;   // wave inclusive totals
    __syncthreads();
    if (tid == 0) {
        int a = 0;
#pragma unroll
        for (int i = 0; i < 4; i++) { int t = wsum[i]; wsum[i] = a; a += t; }
        wsum[4] = a;
    }
    __syncthreads();
    total = wsum[4];
    return x - v + wsum[tid >> 6];
}

// ---------------- k_count: global degree histogram (distributed atomics) ----------------
__global__ __launch_bounds__(256) void k_count(const int* __restrict__ dst,
                                               int* __restrict__ deg, int E) {
    int e = blockIdx.x * 1024 + (threadIdx.x << 2);
    if (e + 3 < E) {
        int4 d = *(const int4*)&dst[e];
        atomicAdd(&deg[d.x], 1);
        atomicAdd(&deg[d.y], 1);
        atomicAdd(&deg[d.z], 1);
        atomicAdd(&deg[d.w], 1);
    } else {
#pragma unroll
        for (int k = 0; k < 4; k++) {
            int ee = e + k;
            if (ee < E) atomicAdd(&deg[dst[ee]], 1);
        }
    }
}

// ---------------- k_scan1: per-block scan of padded degrees ----------------
__global__ __launch_bounds__(256) void k_scan1(const int* __restrict__ deg,
                                               int* __restrict__ offsL,
                                               int* __restrict__ blockTot, int N) {
    __shared__ int wsum[5];
    int tid = threadIdx.x, b = blockIdx.x;
    int node = b * 256 + tid;
    int dg = (node < N) ? deg[node] : 0;
    int pad = (dg + 3) & ~3;                       // pad-to-4 for ushort4 hops
    int total;
    int excl = block_scan_excl(pad, tid, wsum, total);
    if (node < N) offsL[node] = excl;
    if (tid == 0) blockTot[b] = total;
}

// ------- k_scan2: global offsets, meta, cursor init, sentinels, q0 -------
__global__ __launch_bounds__(256) void k_scan2(
        const int* __restrict__ deg, const int* __restrict__ offsL,
        const int* __restrict__ blockTot, const float* __restrict__ x,
        int2* __restrict__ meta, int* __restrict__ cursor,
        unsigned short* __restrict__ csr,
        float2* __restrict__ q0, float2* __restrict__ q1, float2* __restrict__ q2,
        int N, int NBL) {
    __shared__ int tot[256], wred[4];
    int tid = threadIdx.x, b = blockIdx.x;
    tot[tid] = (tid < NBL) ? blockTot[tid] : 0;
    __syncthreads();
    int part = (tid < b) ? tot[tid] : 0;           // base = sum of preceding block totals
#pragma unroll
    for (int m = 32; m > 0; m >>= 1) part += __shfl_xor(part, m);
    if ((tid & 63) == 0) wred[tid >> 6] = part;
    __syncthreads();
    int base = wred[0] + wred[1] + wred[2] + wred[3];
    int node = b * 256 + tid;
    if (node < N) {
        int dg = deg[node];
        int offs = base + offsL[node];             // multiple of 4
        meta[node] = make_int2(offs, dg);
        cursor[node] = offs;
        float dv = rsqrtf((float)(dg + 1));        // +1 self loop
        q0[node] = make_float2(x[node] * dv, dv);
        int pad = (dg + 3) & ~3;
        for (int p = dg; p < pad; p++) csr[offs + p] = (unsigned short)N;  // sentinels
    }
    if (b == 0 && tid == 0) {
        q0[N] = make_float2(0.f, 0.f);
        q1[N] = make_float2(0.f, 0.f);
        q2[N] = make_float2(0.f, 0.f);
    }
}

// ------- k_scatter: csr[atomic cursor++] = src; extra last block = weight chain -------
__global__ __launch_bounds__(256) void k_scatter_chain(
        const int* __restrict__ src, const int* __restrict__ dst,
        int* __restrict__ cursor, unsigned short* __restrict__ csr, int E, int nseg,
        const float* __restrict__ lin_w, const float* __restrict__ lin_b,
        const float* __restrict__ gcn_w, const float* __restrict__ gcn_b,
        float* __restrict__ chainv) {
    __shared__ float v4[512];
    int tid = threadIdx.x;
    if ((int)blockIdx.x == nseg) {
        // ---- weight chain: 4 vectors of 128 through 3 layers (validated R1-R10) ----
        int j = tid & 127, gg = tid >> 7;   // gg in {0,1}; thread owns vecs {gg, gg+2}
        if (tid < 128) {
            v4[tid]       = lin_w[tid];
            v4[128 + tid] = lin_b[tid];
            v4[256 + tid] = gcn_b[tid];        // b1
            v4[384 + tid] = gcn_b[128 + tid];  // b2
        }
        __syncthreads();
        for (int l = 0; l < 3; l++) {
            const float* W = gcn_w + l * 128 * 128;
            float a0 = 0.f, a1 = 0.f;
            for (int k0 = 0; k0 < 128; k0 += 16) {
                float wreg[16];
#pragma unroll
                for (int t = 0; t < 16; t++) wreg[t] = W[(k0 + t) * 128 + j];
#pragma unroll
                for (int t = 0; t < 16; t++) {
                    a0 += v4[gg * 128 + k0 + t] * wreg[t];
                    a1 += v4[(gg + 2) * 128 + k0 + t] * wreg[t];
                }
            }
            __syncthreads();
            v4[gg * 128 + j] = a0;
            bool upd = (gg == 0) ? (l >= 1) : (l >= 2);
            if (upd) v4[(gg + 2) * 128 + j] = a1;
            __syncthreads();
        }
        chainv[tid]       = v4[tid];
        chainv[256 + tid] = v4[256 + tid];
        return;
    }
    int e = blockIdx.x * 1024 + (tid << 2);
    if (e + 3 < E) {
        int4 d = *(const int4*)&dst[e];
        int4 s = *(const int4*)&src[e];
        int p0 = atomicAdd(&cursor[d.x], 1); csr[p0] = (unsigned short)s.x;
        int p1 = atomicAdd(&cursor[d.y], 1); csr[p1] = (unsigned short)s.y;
        int p2 = atomicAdd(&cursor[d.z], 1); csr[p2] = (unsigned short)s.z;
        int p3 = atomicAdd(&cursor[d.w], 1); csr[p3] = (unsigned short)s.w;
    } else {
#pragma unroll
        for (int k = 0; k < 4; k++) {
            int ee = e + k;
            if (ee < E) {
                int p = atomicAdd(&cursor[dst[ee]], 1);
                csr[p] = (unsigned short)src[ee];
            }
        }
    }
}

// ---------------- hop1: 8 lanes/node, 1 ushort4 + 4 gathers per lane-round ----------------
__global__ __launch_bounds__(256) void k_hop1(
        const float2* __restrict__ qin, float2* __restrict__ outv,
        const unsigned short* __restrict__ csr,
        const int2* __restrict__ meta, int N) {
    int tid  = threadIdx.x;
    int lane = tid & 7;
    int node = blockIdx.x * 32 + (tid >> 3);
    if (node >= N) return;
    int2 md = meta[node];
    int e = md.x, ne = md.y;              // e % 4 == 0; slot padded with sentinels
    float sx = 0.0f, su = 0.0f;
    for (int j = 4 * lane; j < ne; j += 32) {
        ushort4 c = *(const ushort4*)&csr[e + j];        // pads -> qin[N] == (0,0)
        float2 a0 = qin[c.x], a1 = qin[c.y], a2 = qin[c.z], a3 = qin[c.w];
        sx += (a0.x + a1.x) + (a2.x + a3.x);
        su += (a0.y + a1.y) + (a2.y + a3.y);
    }
#pragma unroll
    for (int m = 4; m > 0; m >>= 1) {
        sx += __shfl_xor(sx, m);
        su += __shfl_xor(su, m);
    }
    if (lane == 0) {
        float2 qs = qin[node];
        float dv = rsqrtf((float)(ne + 1));
        float px = dv * (sx + qs.x), pu = dv * (su + qs.y);
        outv[node] = make_float2(px * dv, pu * dv);
    }
}

// ---- hop2: writes q2; per-BLOCK per-graph partials of su1 to distinct slots ----
__global__ __launch_bounds__(256) void k_hop2(
        const float2* __restrict__ qin, float2* __restrict__ outv,
        const unsigned short* __restrict__ csr,
        const int2* __restrict__ meta, const int* __restrict__ batch,
        float* __restrict__ gp1, int N, int NBLK) {
    __shared__ float aS[NGRAPH];
    int tid  = threadIdx.x;
    int lane = tid & 7;
    int node = blockIdx.x * 32 + (tid >> 3);
    if (tid < NGRAPH) aS[tid] = 0.f;
    __syncthreads();
    if (node < N) {
        int2 md = meta[node];
        int e = md.x, ne = md.y;
        float sx = 0.0f, su = 0.0f;
        for (int j = 4 * lane; j < ne; j += 32) {
            ushort4 c = *(const ushort4*)&csr[e + j];
            float2 a0 = qin[c.x], a1 = qin[c.y], a2 = qin[c.z], a3 = qin[c.w];
            sx += (a0.x + a1.x) + (a2.x + a3.x);
            su += (a0.y + a1.y) + (a2.y + a3.y);
        }
#pragma unroll
        for (int m = 4; m > 0; m >>= 1) {
            sx += __shfl_xor(sx, m);
            su += __shfl_xor(su, m);
        }
        if (lane == 0) {
            float2 qs = qin[node];            // q1[node]
            float dv = rsqrtf((float)(ne + 1));
            float px = dv * (sx + qs.x), pu = dv * (su + qs.y);
            outv[node] = make_float2(px * dv, pu * dv);
            atomicAdd(&aS[batch[node]], qs.y * sqrtf((float)(ne + 1)));  // su1 (LDS)
        }
    }
    __syncthreads();
    if (tid < NGRAPH) gp1[tid * NBLK + blockIdx.x] = aS[tid];   // distinct slot per block
}

// ---- hop3: no per-node output; per-block partials of su2, sv3, su3 ----
__global__ __launch_bounds__(256) void k_hop3(
        const float2* __restrict__ qin,
        const unsigned short* __restrict__ csr,
        const int2* __restrict__ meta, const int* __restrict__ batch,
        float* __restrict__ gp2, float* __restrict__ gp3, float* __restrict__ gp4,
        int N, int NBLK) {
    __shared__ float aS[NGRAPH], aV[NGRAPH], aU[NGRAPH];
    int tid  = threadIdx.x;
    int lane = tid & 7;
    int node = blockIdx.x * 32 + (tid >> 3);
    if (tid < NGRAPH) { aS[tid] = 0.f; aV[tid] = 0.f; aU[tid] = 0.f; }
    __syncthreads();
    if (node < N) {
        int2 md = meta[node];
        int e = md.x, ne = md.y;
        float sx = 0.0f, su = 0.0f;
        for (int j = 4 * lane; j < ne; j += 32) {
            ushort4 c = *(const ushort4*)&csr[e + j];
            float2 a0 = qin[c.x], a1 = qin[c.y], a2 = qin[c.z], a3 = qin[c.w];
            sx += (a0.x + a1.x) + (a2.x + a3.x);
            su += (a0.y + a1.y) + (a2.y + a3.y);
        }
#pragma unroll
        for (int m = 4; m > 0; m >>= 1) {
            sx += __shfl_xor(sx, m);
            su += __shfl_xor(su, m);
        }
        if (lane == 0) {
            float2 qs = qin[node];            // q2[node]
            float dv = rsqrtf((float)(ne + 1));
            float px = dv * (sx + qs.x), pu = dv * (su + qs.y);  // p3 values
            int g = batch[node];
            atomicAdd(&aS[g], qs.y * sqrtf((float)(ne + 1)));    // su2 (LDS)
            atomicAdd(&aV[g], px);                               // sv3
            atomicAdd(&aU[g], pu);                               // su3
        }
    }
    __syncthreads();
    if (tid < NGRAPH) {
        int slot = tid * NBLK + blockIdx.x;
        gp2[slot] = aS[tid];
        gp3[slot] = aV[tid];
        gp4[slot] = aU[tid];
    }
}

// ------- readout: reduce per-block partials + MLP; graph size via binary search -------
__global__ __launch_bounds__(256) void k_mlp(
        const int* __restrict__ batch, const float* __restrict__ chainv,
        const float* __restrict__ gp1, const float* __restrict__ gp2,
        const float* __restrict__ gp3, const float* __restrict__ gp4,
        const float* __restrict__ gcn_b,
        const float* __restrict__ r1_w, const float* __restrict__ r1_b,
        const float* __restrict__ r2_w, const float* __restrict__ r2_b,
        float* __restrict__ out, int NBLK, int N) {
    __shared__ float pl[128], red[128], r4[256];
    __shared__ float cntSh;
    int tid = threadIdx.x;
    int g = blockIdx.x;
    if (tid == 0) {       // batch is sorted: cnt = ub(g) - lb(g)
        int lo = 0, hi = N;
        while (lo < hi) { int m = (lo + hi) >> 1; if (batch[m] < g) lo = m + 1; else hi = m; }
        int lb = lo; lo = 0; hi = N;
        while (lo < hi) { int m = (lo + hi) >> 1; if (batch[m] < g + 1) lo = m + 1; else hi = m; }
        cntSh = (float)(lo - lb);
    }
    float su1 = 0.f, su2 = 0.f, sv3 = 0.f, su3 = 0.f;
    for (int b = tid; b < NBLK; b += BLK) {      // contiguous per-graph rows, coalesced
        su1 += gp1[g * NBLK + b];
        su2 += gp2[g * NBLK + b];
        sv3 += gp3[g * NBLK + b];
        su3 += gp4[g * NBLK + b];
    }
#pragma unroll
    for (int m = 32; m > 0; m >>= 1) {
        su1 += __shfl_xor(su1, m);
        su2 += __shfl_xor(su2, m);
        su3 += __shfl_xor(su3, m);
        sv3 += __shfl_xor(sv3, m);
    }
    int wv = tid >> 6;
    if ((tid & 63) == 0) {
        r4[wv] = su1; r4[4 + wv] = su2; r4[8 + wv] = su3; r4[12 + wv] = sv3;
    }
    __syncthreads();
    su1 = r4[0] + r4[1] + r4[2] + r4[3];
    su2 = r4[4] + r4[5] + r4[6] + r4[7];
    su3 = r4[8] + r4[9] + r4[10] + r4[11];
    sv3 = r4[12] + r4[13] + r4[14] + r4[15];
    float cnt = cntSh;
    const float* b3 = gcn_b + 2 * 128;
    if (tid < 128)
        pl[tid] = sv3 * chainv[tid] + su3 * chainv[128 + tid] + su2 * chainv[256 + tid]
                + su1 * chainv[384 + tid] + cnt * b3[tid];
    __syncthreads();
    int j = tid & 127, half = tid >> 7;
    float acc = 0.f;
#pragma unroll 8
    for (int kk = 0; kk < 64; kk++) {
        int k = half * 64 + kk;
        acc += pl[k] * r1_w[k * 128 + j];   // coalesced, L2-resident across 32 blocks
    }
    r4[half * 128 + j] = acc;
    __syncthreads();
    if (tid < 128) {
        float a = r4[tid] + r4[128 + tid] + r1_b[tid];
        red[tid] = tanhf(a) * r2_w[tid];
    }
    __syncthreads();
    for (int sft = 64; sft > 0; sft >>= 1) {
        if (tid < sft) red[tid] += red[tid + sft];
        __syncthreads();
    }
    if (tid == 0) out[g] = red[0] + r2_b[0];
}

extern "C" void kernel_launch(void* const* d_in, const int* in_sizes, int n_in,
                              void* d_out, int out_size, void* d_ws, size_t ws_size,
                              hipStream_t stream) {
    const float* x     = (const float*)d_in[0];
    const int*   eidx  = (const int*)d_in[1];
    const int*   batch = (const int*)d_in[2];
    const float* lin_w = (const float*)d_in[3];
    const float* lin_b = (const float*)d_in[4];
    const float* gcn_w = (const float*)d_in[5];
    const float* gcn_b = (const float*)d_in[6];
    const float* r1_w  = (const float*)d_in[7];
    const float* r1_b  = (const float*)d_in[8];
    const float* r2_w  = (const float*)d_in[9];
    const float* r2_b  = (const float*)d_in[10];

    const int N = in_sizes[0];
    const int E = in_sizes[1] / 2;
    const int* src = eidx;
    const int* dst = eidx + E;
    const int NBL = (N + 255) / 256;          // 196 scan blocks
    const int hop_blocks = (N + 31) / 32;     // 1563
    const int nseg = (E + 1023) / 1024;       // 1563 edge segments

    // workspace layout: 8B types, then 4B, then 2B csr last (csr base 8B-aligned)
    char* w = (char*)d_ws;
    float2* q0      = (float2*)w; w += (size_t)(N + 2) * 8;
    float2* q1      = (float2*)w; w += (size_t)(N + 2) * 8;
    float2* q2      = (float2*)w; w += (size_t)(N + 2) * 8;
    int2*   meta    = (int2*)w;   w += (size_t)N * 8;
    int*    deg     = (int*)w;    w += (size_t)N * 4;       // zeroed each call
    int*    offsL   = (int*)w;    w += (size_t)N * 4;
    int*    cursor  = (int*)w;    w += (size_t)N * 4;
    int*    blockTot= (int*)w;    w += 256 * 4;
    float*  gp1     = (float*)w;  w += (size_t)NGRAPH * hop_blocks * 4;  // no pre-zero needed
    float*  gp2     = (float*)w;  w += (size_t)NGRAPH * hop_blocks * 4;
    float*  gp3     = (float*)w;  w += (size_t)NGRAPH * hop_blocks * 4;
    float*  gp4     = (float*)w;  w += (size_t)NGRAPH * hop_blocks * 4;
    float*  chainv  = (float*)w;  w += 512 * 4;
    unsigned short* csr = (unsigned short*)w; w += ((size_t)E + 4 * N) * 2 + 256;

    hipMemsetAsync(deg, 0, (size_t)N * 4, stream);

    k_count<<<nseg, 256, 0, stream>>>(dst, deg, E);
    k_scan1<<<NBL, 256, 0, stream>>>(deg, offsL, blockTot, N);
    k_scan2<<<NBL, 256, 0, stream>>>(deg, offsL, blockTot, x, meta, cursor, csr,
                                     q0, q1, q2, N, NBL);
    k_scatter_chain<<<nseg + 1, 256, 0, stream>>>(src, dst, cursor, csr, E, nseg,
                                                  lin_w, lin_b, gcn_w, gcn_b, chainv);

    k_hop1<<<hop_blocks, 256, 0, stream>>>(q0, q1, csr, meta, N);
    k_hop2<<<hop_blocks, 256, 0, stream>>>(q1, q2, csr, meta, batch, gp1, N, hop_blocks);
    k_hop3<<<hop_blocks, 256, 0, stream>>>(q2, csr, meta, batch, gp2, gp3, gp4,
                                           N, hop_blocks);

    k_mlp<<<NGRAPH, 256, 0, stream>>>(batch, chainv, gp1, gp2, gp3, gp4, gcn_b,
                                      r1_w, r1_b, r2_w, r2_b, (float*)d_out,
                                      hop_blocks, N);
}

// Round 12
// 148.574 us; speedup vs baseline: 1.9322x; 1.9322x over previous
//
#include <hip/hip_runtime.h>
#include <math.h>

#define NGRAPH 32
#define CAP 10240        // edge capacity per bucket (mean ~8192 + pad<=3/node, ~12 sigma)
#define EPT 16           // edges per thread in k_part (392 blocks)
#define EPB (256 * EPT)  // 4096 edges per partition block
#define BLK 256

// ---- block-wide exclusive scan over 256 threads, 2 barriers (shfl-based) ----
__device__ __forceinline__ int block_scan_excl(int v, int tid, int* wsum, int& total) {
    int x = v;
#pragma unroll
    for (int d = 1; d < 64; d <<= 1) {
        int t = __shfl_up(x, d);
        if ((tid & 63) >= d) x += t;
    }
    if ((tid & 63) == 63) wsum[tid >> 6] = x;   // wave inclusive totals
    __syncthreads();
    if (tid == 0) {
        int a = 0;
#pragma unroll
        for (int i = 0; i < 4; i++) { int t = wsum[i]; wsum[i] = a; a += t; }
        wsum[4] = a;
    }
    __syncthreads();
    total = wsum[4];
    return x - v + wsum[tid >> 6];
}

// ---------------- pure edge partition into fixed-capacity bucket ranges ----------------
// staged word: (bucket << 24) | (src << 8) | (dst & 255)   [src < 65536]
// gcursor padded to 1 int per 64B line (stride 16) to kill same-line atomic contention.
__global__ __launch_bounds__(256, 4) void k_part(
        const int* __restrict__ src, const int* __restrict__ dst,
        int* __restrict__ gcursor, unsigned int* __restrict__ packed, int E) {
    __shared__ unsigned int ldsbuf[EPB];   // 16 KB
    __shared__ int hist[256], lofs[256], lcur[256], base[256], wsum[5];
    int tid = threadIdx.x;
    int e0 = blockIdx.x * EPB;
    hist[tid] = 0;
    __syncthreads();
    int d_[EPT], s_[EPT];
#pragma unroll
    for (int c = 0; c < EPT / 4; c++) {
        int e = e0 + c * 1024 + (tid << 2);
        if (e + 3 < E) {
            int4 dv = *(const int4*)&dst[e];
            int4 sv = *(const int4*)&src[e];
            d_[4*c+0] = dv.x; d_[4*c+1] = dv.y; d_[4*c+2] = dv.z; d_[4*c+3] = dv.w;
            s_[4*c+0] = sv.x; s_[4*c+1] = sv.y; s_[4*c+2] = sv.z; s_[4*c+3] = sv.w;
            atomicAdd(&hist[dv.x >> 8], 1);
            atomicAdd(&hist[dv.y >> 8], 1);
            atomicAdd(&hist[dv.z >> 8], 1);
            atomicAdd(&hist[dv.w >> 8], 1);
        } else {
#pragma unroll
            for (int k = 0; k < 4; k++) {
                int ee = e + k;
                if (ee < E) {
                    d_[4*c+k] = dst[ee]; s_[4*c+k] = src[ee];
                    atomicAdd(&hist[d_[4*c+k] >> 8], 1);
                } else {
                    d_[4*c+k] = -1;
                }
            }
        }
    }
    __syncthreads();
    int v = hist[tid];
    int total;
    int excl = block_scan_excl(v, tid, wsum, total);
    lofs[tid] = excl;
    lcur[tid] = excl;
    if (v > 0) base[tid] = tid * CAP + atomicAdd(&gcursor[tid << 4], v);  // padded line
    __syncthreads();
#pragma unroll
    for (int c = 0; c < EPT; c++) {
        int dd = d_[c];
        if (dd >= 0) {
            int bk = dd >> 8;
            int slot = atomicAdd(&lcur[bk], 1);
            ldsbuf[slot] = ((unsigned int)bk << 24) | ((unsigned int)s_[c] << 8)
                         | (unsigned int)(dd & 255);
        }
    }
    __syncthreads();
    for (int i = tid; i < total; i += BLK) {
        unsigned int w = ldsbuf[i];
        int bk = w >> 24;
        packed[base[bk] + (i - lofs[bk])] = w & 0xFFFFFFu;
    }
}

// ------- per-bucket CSR build in LDS (pad-to-4, sentinels), coalesced out -------
// writes meta[node] = {offs, deg}; dinv is recomputed in hops as rsqrtf(deg+1).
// extra last block (blockIdx == NB) computes the weight-chain vectors instead.
__global__ __launch_bounds__(256) void k_bucket_chain(
        const unsigned int* __restrict__ packed, const int* __restrict__ gcursor,
        const float* __restrict__ x, const int* __restrict__ batch,
        int2* __restrict__ meta, float2* __restrict__ q0,
        float2* __restrict__ q1, float2* __restrict__ q2,
        unsigned short* __restrict__ csr, float* __restrict__ S, int N, int NB,
        const float* __restrict__ lin_w, const float* __restrict__ lin_b,
        const float* __restrict__ gcn_w, const float* __restrict__ gcn_b,
        float* __restrict__ chainv) {
    __shared__ union {
        struct {
            unsigned int buf[CAP];                       // 40 KB: single global pass
            __align__(16) unsigned short lcsr[CAP];      // 20 KB: CSR staged in LDS
            int cnt[256], lcur[256], wsum[5];
            float cs[NGRAPH];
        } b;
        struct { float v4[512]; } c;
    } sm;
    int tid = threadIdx.x;
    int b = blockIdx.x;

    if (b == NB) {
        // ---- weight chain: 4 vectors of 128 through 3 layers (validated R1-R8) ----
        float* v4 = sm.c.v4;
        int j = tid & 127, gg = tid >> 7;   // gg in {0,1}; thread owns vecs {gg, gg+2}
        if (tid < 128) {
            v4[tid]       = lin_w[tid];
            v4[128 + tid] = lin_b[tid];
            v4[256 + tid] = gcn_b[tid];        // b1
            v4[384 + tid] = gcn_b[128 + tid];  // b2
        }
        __syncthreads();
        for (int l = 0; l < 3; l++) {
            const float* W = gcn_w + l * 128 * 128;
            float a0 = 0.f, a1 = 0.f;
            for (int k0 = 0; k0 < 128; k0 += 16) {   // 16 loads in flight per batch
                float wreg[16];
#pragma unroll
                for (int t = 0; t < 16; t++) wreg[t] = W[(k0 + t) * 128 + j];
#pragma unroll
                for (int t = 0; t < 16; t++) {
                    a0 += v4[gg * 128 + k0 + t] * wreg[t];
                    a1 += v4[(gg + 2) * 128 + k0 + t] * wreg[t];
                }
            }
            __syncthreads();
            v4[gg * 128 + j] = a0;             // vec0 (w-chain), vec1 (b-chain): always
            bool upd = (gg == 0) ? (l >= 1) : (l >= 2);  // vec2 from l>=1, vec3 from l>=2
            if (upd) v4[(gg + 2) * 128 + j] = a1;
            __syncthreads();
        }
        chainv[tid]       = v4[tid];
        chainv[256 + tid] = v4[256 + tid];
        return;
    }

    int start = b * CAP;
    int len = gcursor[b << 4];            // padded line stride
    sm.b.cnt[tid] = 0;
    if (tid < NGRAPH) sm.b.cs[tid] = 0.f;
    __syncthreads();
    for (int e = tid; e < len; e += BLK) {
        unsigned int w = packed[start + e];
        sm.b.buf[e] = w;
        atomicAdd(&sm.b.cnt[w & 255], 1);
    }
    __syncthreads();
    int v = sm.b.cnt[tid];
    int vp = (v + 3) & ~3;          // pad each node's slot to multiple of 4
    int total;
    int excl = block_scan_excl(vp, tid, sm.b.wsum, total);  // multiple of 4 per node
    sm.b.lcur[tid] = excl;
    int node = b * 256 + tid;
    if (node < N) {
        meta[node] = make_int2(start + excl, v);
        float dv = rsqrtf((float)(v + 1));   // +1 self loop
        q0[node] = make_float2(x[node] * dv, dv);
        atomicAdd(&sm.b.cs[batch[node]], 1.f);
        for (int p = v; p < vp; p++)          // 0..3 sentinel pads -> q[N]=(0,0)
            sm.b.lcsr[excl + p] = (unsigned short)N;
    }
    if (b == 0 && tid == 0) {
        q0[N] = make_float2(0.f, 0.f);
        q1[N] = make_float2(0.f, 0.f);
        q2[N] = make_float2(0.f, 0.f);
    }
    __syncthreads();
    for (int e = tid; e < len; e += BLK) {
        unsigned int w = sm.b.buf[e];
        sm.b.lcsr[atomicAdd(&sm.b.lcur[w & 255], 1)] = (unsigned short)(w >> 8);
    }
    if (tid < NGRAPH && sm.b.cs[tid] != 0.f) atomicAdd(&S[tid], sm.b.cs[tid]);
    __syncthreads();
    // coalesced copy-out: total entries, multiple of 4 (8 B chunks)
    const uint2* ls = (const uint2*)sm.b.lcsr;
    uint2* gs = (uint2*)&csr[start];        // start*2 bytes, multiple of 8
    for (int i = tid; i < (total >> 2); i += BLK) gs[i] = ls[i];
}

// ---------------- hop1: 8 lanes/node, 1 ushort4 + 4 gathers per lane-round ----------------
__global__ __launch_bounds__(256) void k_hop1(
        const float2* __restrict__ qin, float2* __restrict__ outv,
        const unsigned short* __restrict__ csr,
        const int2* __restrict__ meta, int N) {
    int tid  = threadIdx.x;
    int lane = tid & 7;
    int node = blockIdx.x * 32 + (tid >> 3);
    if (node >= N) return;
    int2 md = meta[node];
    int e = md.x, ne = md.y;              // e % 4 == 0; slot padded with sentinels
    float sx = 0.0f, su = 0.0f;
    for (int j = 4 * lane; j < ne; j += 32) {
        ushort4 c = *(const ushort4*)&csr[e + j];        // pads -> qin[N] == (0,0)
        float2 a0 = qin[c.x], a1 = qin[c.y], a2 = qin[c.z], a3 = qin[c.w];
        sx += (a0.x + a1.x) + (a2.x + a3.x);
        su += (a0.y + a1.y) + (a2.y + a3.y);
    }
#pragma unroll
    for (int m = 4; m > 0; m >>= 1) {
        sx += __shfl_xor(sx, m);
        su += __shfl_xor(su, m);
    }
    if (lane == 0) {
        float2 qs = qin[node];
        float dv = rsqrtf((float)(ne + 1));
        float px = dv * (sx + qs.x), pu = dv * (su + qs.y);
        outv[node] = make_float2(px * dv, pu * dv);
    }
}

// ---- hop2: writes q2; per-BLOCK per-graph partials of su1 to distinct slots ----
__global__ __launch_bounds__(256) void k_hop2(
        const float2* __restrict__ qin, float2* __restrict__ outv,
        const unsigned short* __restrict__ csr,
        const int2* __restrict__ meta, const int* __restrict__ batch,
        float* __restrict__ gp1, int N, int NBLK) {
    __shared__ float aS[NGRAPH];
    int tid  = threadIdx.x;
    int lane = tid & 7;
    int node = blockIdx.x * 32 + (tid >> 3);
    if (tid < NGRAPH) aS[tid] = 0.f;
    __syncthreads();
    if (node < N) {
        int2 md = meta[node];
        int e = md.x, ne = md.y;
        float sx = 0.0f, su = 0.0f;
        for (int j = 4 * lane; j < ne; j += 32) {
            ushort4 c = *(const ushort4*)&csr[e + j];
            float2 a0 = qin[c.x], a1 = qin[c.y], a2 = qin[c.z], a3 = qin[c.w];
            sx += (a0.x + a1.x) + (a2.x + a3.x);
            su += (a0.y + a1.y) + (a2.y + a3.y);
        }
#pragma unroll
        for (int m = 4; m > 0; m >>= 1) {
            sx += __shfl_xor(sx, m);
            su += __shfl_xor(su, m);
        }
        if (lane == 0) {
            float2 qs = qin[node];            // q1[node]
            float dv = rsqrtf((float)(ne + 1));
            float px = dv * (sx + qs.x), pu = dv * (su + qs.y);
            outv[node] = make_float2(px * dv, pu * dv);
            atomicAdd(&aS[batch[node]], qs.y * sqrtf((float)(ne + 1)));  // su1 (LDS)
        }
    }
    __syncthreads();
    if (tid < NGRAPH) gp1[tid * NBLK + blockIdx.x] = aS[tid];   // distinct slot per block
}

// ---- hop3: no per-node output; per-block partials of su2, sv3, su3 ----
__global__ __launch_bounds__(256) void k_hop3(
        const float2* __restrict__ qin,
        const unsigned short* __restrict__ csr,
        const int2* __restrict__ meta, const int* __restrict__ batch,
        float* __restrict__ gp2, float* __restrict__ gp3, float* __restrict__ gp4,
        int N, int NBLK) {
    __shared__ float aS[NGRAPH], aV[NGRAPH], aU[NGRAPH];
    int tid  = threadIdx.x;
    int lane = tid & 7;
    int node = blockIdx.x * 32 + (tid >> 3);
    if (tid < NGRAPH) { aS[tid] = 0.f; aV[tid] = 0.f; aU[tid] = 0.f; }
    __syncthreads();
    if (node < N) {
        int2 md = meta[node];
        int e = md.x, ne = md.y;
        float sx = 0.0f, su = 0.0f;
        for (int j = 4 * lane; j < ne; j += 32) {
            ushort4 c = *(const ushort4*)&csr[e + j];
            float2 a0 = qin[c.x], a1 = qin[c.y], a2 = qin[c.z], a3 = qin[c.w];
            sx += (a0.x + a1.x) + (a2.x + a3.x);
            su += (a0.y + a1.y) + (a2.y + a3.y);
        }
#pragma unroll
        for (int m = 4; m > 0; m >>= 1) {
            sx += __shfl_xor(sx, m);
            su += __shfl_xor(su, m);
        }
        if (lane == 0) {
            float2 qs = qin[node];            // q2[node]
            float dv = rsqrtf((float)(ne + 1));
            float px = dv * (sx + qs.x), pu = dv * (su + qs.y);  // p3 values
            int g = batch[node];
            atomicAdd(&aS[g], qs.y * sqrtf((float)(ne + 1)));    // su2 (LDS)
            atomicAdd(&aV[g], px);                               // sv3
            atomicAdd(&aU[g], pu);                               // su3
        }
    }
    __syncthreads();
    if (tid < NGRAPH) {
        int slot = tid * NBLK + blockIdx.x;
        gp2[slot] = aS[tid];
        gp3[slot] = aV[tid];
        gp4[slot] = aU[tid];
    }
}

// ---------------- readout: reduce per-block partials + MLP ----------------
__global__ __launch_bounds__(256) void k_mlp(
        const float* __restrict__ S, const float* __restrict__ chainv,
        const float* __restrict__ gp1, const float* __restrict__ gp2,
        const float* __restrict__ gp3, const float* __restrict__ gp4,
        const float* __restrict__ gcn_b,
        const float* __restrict__ r1_w, const float* __restrict__ r1_b,
        const float* __restrict__ r2_w, const float* __restrict__ r2_b,
        float* __restrict__ out, int NBLK) {
    __shared__ float pl[128], red[128], r4[256];
    int tid = threadIdx.x;
    int g = blockIdx.x;
    float su1 = 0.f, su2 = 0.f, sv3 = 0.f, su3 = 0.f;
    for (int b = tid; b < NBLK; b += BLK) {      // contiguous per-graph rows, coalesced
        su1 += gp1[g * NBLK + b];
        su2 += gp2[g * NBLK + b];
        sv3 += gp3[g * NBLK + b];
        su3 += gp4[g * NBLK + b];
    }
#pragma unroll
    for (int m = 32; m > 0; m >>= 1) {
        su1 += __shfl_xor(su1, m);
        su2 += __shfl_xor(su2, m);
        su3 += __shfl_xor(su3, m);
        sv3 += __shfl_xor(sv3, m);
    }
    int wv = tid >> 6;
    if ((tid & 63) == 0) {
        r4[wv] = su1; r4[4 + wv] = su2; r4[8 + wv] = su3; r4[12 + wv] = sv3;
    }
    __syncthreads();
    su1 = r4[0] + r4[1] + r4[2] + r4[3];
    su2 = r4[4] + r4[5] + r4[6] + r4[7];
    su3 = r4[8] + r4[9] + r4[10] + r4[11];
    sv3 = r4[12] + r4[13] + r4[14] + r4[15];
    float cnt = S[g];
    const float* b3 = gcn_b + 2 * 128;
    if (tid < 128)
        pl[tid] = sv3 * chainv[tid] + su3 * chainv[128 + tid] + su2 * chainv[256 + tid]
                + su1 * chainv[384 + tid] + cnt * b3[tid];
    __syncthreads();
    int j = tid & 127, half = tid >> 7;
    float acc = 0.f;
#pragma unroll 8
    for (int kk = 0; kk < 64; kk++) {
        int k = half * 64 + kk;
        acc += pl[k] * r1_w[k * 128 + j];   // coalesced, L2-resident across 32 blocks
    }
    r4[half * 128 + j] = acc;
    __syncthreads();
    if (tid < 128) {
        float a = r4[tid] + r4[128 + tid] + r1_b[tid];
        red[tid] = tanhf(a) * r2_w[tid];
    }
    __syncthreads();
    for (int sft = 64; sft > 0; sft >>= 1) {
        if (tid < sft) red[tid] += red[tid + sft];
        __syncthreads();
    }
    if (tid == 0) out[g] = red[0] + r2_b[0];
}

extern "C" void kernel_launch(void* const* d_in, const int* in_sizes, int n_in,
                              void* d_out, int out_size, void* d_ws, size_t ws_size,
                              hipStream_t stream) {
    const float* x     = (const float*)d_in[0];
    const int*   eidx  = (const int*)d_in[1];
    const int*   batch = (const int*)d_in[2];
    const float* lin_w = (const float*)d_in[3];
    const float* lin_b = (const float*)d_in[4];
    const float* gcn_w = (const float*)d_in[5];
    const float* gcn_b = (const float*)d_in[6];
    const float* r1_w  = (const float*)d_in[7];
    const float* r1_b  = (const float*)d_in[8];
    const float* r2_w  = (const float*)d_in[9];
    const float* r2_b  = (const float*)d_in[10];

    const int N = in_sizes[0];
    const int E = in_sizes[1] / 2;
    const int* src = eidx;
    const int* dst = eidx + E;
    const int NB = (N + 255) / 256;       // 196 buckets
    const int hop_blocks = (N + 31) / 32; // 1563

    // workspace layout: 8B-aligned types first, 4B, then 2B csr last (csr base 16B-aligned)
    char* w = (char*)d_ws;
    float2* q0      = (float2*)w; w += (size_t)(N + 2) * 8;
    float2* q1      = (float2*)w; w += (size_t)(N + 2) * 8;
    float2* q2      = (float2*)w; w += (size_t)(N + 2) * 8;
    int2*   meta    = (int2*)w;   w += (size_t)N * 8;
    unsigned int* packed = (unsigned int*)w; w += (size_t)256 * CAP * 4;
    float*  gp1     = (float*)w;  w += (size_t)NGRAPH * hop_blocks * 4;  // no pre-zero needed
    float*  gp2     = (float*)w;  w += (size_t)NGRAPH * hop_blocks * 4;
    float*  gp3     = (float*)w;  w += (size_t)NGRAPH * hop_blocks * 4;
    float*  gp4     = (float*)w;  w += (size_t)NGRAPH * hop_blocks * 4;
    int*    gcursor = (int*)w;    w += 256 * 16 * 4;  // --- zeroed region start (padded lines) ---
    float*  S       = (float*)w;  w += 64 * 4;        // --- zeroed region end ---
    float*  chainv  = (float*)w;  w += 512 * 4;
    unsigned short* csr = (unsigned short*)w; w += (size_t)256 * CAP * 2 + 256;

    // single memset covers padded gcursor (16 KB) + S (256 B), contiguous
    hipMemsetAsync(gcursor, 0, 256 * 16 * 4 + 64 * 4, stream);

    const int nchunk = (E + EPB - 1) / EPB;   // 391
    k_part<<<nchunk, 256, 0, stream>>>(src, dst, gcursor, packed, E);
    k_bucket_chain<<<NB + 1, 256, 0, stream>>>(packed, gcursor, x, batch, meta,
                                               q0, q1, q2, csr, S, N, NB,
                                               lin_w, lin_b, gcn_w, gcn_b, chainv);

    k_hop1<<<hop_blocks, 256, 0, stream>>>(q0, q1, csr, meta, N);
    k_hop2<<<hop_blocks, 256, 0, stream>>>(q1, q2, csr, meta, batch, gp1, N, hop_blocks);
    k_hop3<<<hop_blocks, 256, 0, stream>>>(q2, csr, meta, batch, gp2, gp3, gp4,
                                           N, hop_blocks);

    k_mlp<<<NGRAPH, 256, 0, stream>>>(S, chainv, gp1, gp2, gp3, gp4, gcn_b,
                                      r1_w, r1_b, r2_w, r2_b, (float*)d_out, hop_blocks);
}